// Round 3
// baseline (111.779 us; speedup 1.0000x reference)
//
#include <hip/hip_runtime.h>
#include <math.h>

// x [B=1024, S=256, E=4] fp32. One block = one batch (256 threads, 4 waves).
// Wave w's lanes hold k/v for rows w*64+lane IN REGISTERS (they computed them
// in phase 1) -- exactly wave w's key chunk. The j-loop broadcasts lane j's
// k/v via v_readlane (uniform j -> SGPR lane operand), so the score/PV FMAs
// read k/v through the free SGPR operand slot: ZERO LDS traffic in the hot
// loop. Only q (cross-wave) and the flash-merge partials go through LDS.
// Scores are computed in exp2 domain (0.5*log2e folded into q) so softmax
// uses v_exp_f32 directly with no per-exp multiply.
constexpr int S  = 256;
constexpr int E  = 4;
constexpr int H1 = 8;
constexpr int H2 = 4;
constexpr int NW    = 4;       // waves per block
constexpr int CHUNK = S / NW;  // 64 keys per wave == 64 lanes
constexpr int R     = 4;       // rows per lane (64 lanes * 4 = 256 rows)

__device__ __forceinline__ float bcast(float v, int lane) {
    return __int_as_float(__builtin_amdgcn_readlane(__float_as_int(v), lane));
}

__global__ __launch_bounds__(256, 4) void attn_mlp_kernel(
    const float* __restrict__ x,
    const float* __restrict__ Wq, const float* __restrict__ Wk, const float* __restrict__ Wv,
    const float* __restrict__ W1, const float* __restrict__ b1,
    const float* __restrict__ W2, const float* __restrict__ b2,
    const float* __restrict__ W3, const float* __restrict__ b3,
    float* __restrict__ out)
{
    const int b    = blockIdx.x;
    const int tid  = threadIdx.x;
    const int lane = tid & 63;

    __shared__ float4 q_lds[S];
    __shared__ float2 ml_lds[NW][S];   // (m, l) partials per scanning wave
    __shared__ float4 acc_lds[NW][S];  // acc partials

    // ---- Phase 1: q/k/v for row tid; k/v stay in registers ----
    const float4 xr = *reinterpret_cast<const float4*>(x + ((size_t)b * S + tid) * E);
    const float xv[E] = {xr.x, xr.y, xr.z, xr.w};
    float4 kreg, vreg;
    {
        float4 q;
        float* qp = &q.x; float* kp = &kreg.x; float* vp = &vreg.x;
        #pragma unroll
        for (int e = 0; e < E; ++e) {
            float aq = 0.f, ak = 0.f, av = 0.f;
            #pragma unroll
            for (int i = 0; i < E; ++i) {
                aq = fmaf(xv[i], Wq[i * E + e], aq);
                ak = fmaf(xv[i], Wk[i * E + e], ak);
                av = fmaf(xv[i], Wv[i * E + e], av);
            }
            qp[e] = aq * (0.5f * 1.44269504f);  // fold 1/sqrt(E) and log2(e)
            kp[e] = ak;
            vp[e] = av;
        }
        q_lds[tid] = q;
    }
    __syncthreads();

    // ---- Phase 2: wave w scans its own 64 keys (in-register) for all 256 rows ----
    const int w = tid >> 6;
    float4 qr[R];
    #pragma unroll
    for (int rr = 0; rr < R; ++rr) qr[rr] = q_lds[lane + 64 * rr];

    float m[R];
    #pragma unroll
    for (int rr = 0; rr < R; ++rr) m[rr] = -3.0e38f;

    #pragma unroll 4
    for (int j = 0; j < CHUNK; ++j) {
        const float kx = bcast(kreg.x, j);
        const float ky = bcast(kreg.y, j);
        const float kz = bcast(kreg.z, j);
        const float kw = bcast(kreg.w, j);
        #pragma unroll
        for (int rr = 0; rr < R; ++rr) {
            float s = qr[rr].x * kx;
            s = fmaf(qr[rr].y, ky, s);
            s = fmaf(qr[rr].z, kz, s);
            s = fmaf(qr[rr].w, kw, s);
            m[rr] = fmaxf(m[rr], s);
        }
    }

    float l[R];
    float4 acc[R];
    #pragma unroll
    for (int rr = 0; rr < R; ++rr) {
        l[rr] = 0.f;
        acc[rr] = make_float4(0.f, 0.f, 0.f, 0.f);
    }

    #pragma unroll 4
    for (int j = 0; j < CHUNK; ++j) {
        const float kx = bcast(kreg.x, j);
        const float ky = bcast(kreg.y, j);
        const float kz = bcast(kreg.z, j);
        const float kw = bcast(kreg.w, j);
        const float vx = bcast(vreg.x, j);
        const float vy = bcast(vreg.y, j);
        const float vz = bcast(vreg.z, j);
        const float vw = bcast(vreg.w, j);
        #pragma unroll
        for (int rr = 0; rr < R; ++rr) {
            float s = qr[rr].x * kx;
            s = fmaf(qr[rr].y, ky, s);
            s = fmaf(qr[rr].z, kz, s);
            s = fmaf(qr[rr].w, kw, s);
            const float p = __builtin_amdgcn_exp2f(s - m[rr]);  // scores in log2 domain
            l[rr] += p;
            acc[rr].x = fmaf(p, vx, acc[rr].x);
            acc[rr].y = fmaf(p, vy, acc[rr].y);
            acc[rr].z = fmaf(p, vz, acc[rr].z);
            acc[rr].w = fmaf(p, vw, acc[rr].w);
        }
    }

    #pragma unroll
    for (int rr = 0; rr < R; ++rr) {
        const int row = lane + 64 * rr;
        ml_lds[w][row]  = make_float2(m[rr], l[rr]);
        acc_lds[w][row] = acc[rr];
    }
    __syncthreads();

    // ---- Phase 3: merge the 4 partials for row tid (exp2 domain), then MLP ----
    float mstar = -3.0e38f;
    float2 mlw[NW];
    #pragma unroll
    for (int ww = 0; ww < NW; ++ww) {
        mlw[ww] = ml_lds[ww][tid];
        mstar = fmaxf(mstar, mlw[ww].x);
    }
    float lsum = 0.f;
    float ax = 0.f, ay = 0.f, az = 0.f, aw = 0.f;
    #pragma unroll
    for (int ww = 0; ww < NW; ++ww) {
        const float c = __builtin_amdgcn_exp2f(mlw[ww].x - mstar);
        lsum = fmaf(mlw[ww].y, c, lsum);
        const float4 a4 = acc_lds[ww][tid];
        ax = fmaf(a4.x, c, ax);
        ay = fmaf(a4.y, c, ay);
        az = fmaf(a4.z, c, az);
        aw = fmaf(a4.w, c, aw);
    }
    const float inv = 1.0f / lsum;
    const float a[E] = {ax * inv, ay * inv, az * inv, aw * inv};

    float h1[H1];
    #pragma unroll
    for (int o = 0; o < H1; ++o) {
        float s = b1[o];
        #pragma unroll
        for (int i = 0; i < E; ++i) s = fmaf(a[i], W1[i * H1 + o], s);
        h1[o] = tanhf(s);
    }
    float h2[H2];
    #pragma unroll
    for (int o = 0; o < H2; ++o) {
        float s = b2[o];
        #pragma unroll
        for (int i = 0; i < H1; ++i) s = fmaf(h1[i], W2[i * H2 + o], s);
        h2[o] = tanhf(s);
    }
    float r = b3[0];
    #pragma unroll
    for (int i = 0; i < H2; ++i) r = fmaf(h2[i], W3[i], r);

    out[(size_t)b * S + tid] = r;
}

extern "C" void kernel_launch(void* const* d_in, const int* in_sizes, int n_in,
                              void* d_out, int out_size, void* d_ws, size_t ws_size,
                              hipStream_t stream) {
    const float* x  = (const float*)d_in[0];
    const float* Wq = (const float*)d_in[1];
    const float* Wk = (const float*)d_in[2];
    const float* Wv = (const float*)d_in[3];
    const float* W1 = (const float*)d_in[4];
    const float* b1 = (const float*)d_in[5];
    const float* W2 = (const float*)d_in[6];
    const float* b2 = (const float*)d_in[7];
    const float* W3 = (const float*)d_in[8];
    const float* b3 = (const float*)d_in[9];
    float* out = (float*)d_out;

    const int B = in_sizes[0] / (S * E);   // 1024
    attn_mlp_kernel<<<dim3(B), dim3(256), 0, stream>>>(
        x, Wq, Wk, Wv, W1, b1, W2, b2, W3, b3, out);
}

// Round 4
// 94.875 us; speedup vs baseline: 1.1782x; 1.1782x over previous
//
#include <hip/hip_runtime.h>
#include <math.h>

// x [B=1024, S=256, E=4] fp32. One block = one batch (256 threads, 4 waves).
// ONE-PASS softmax via per-row upper bound: q.k <= |q| * max_j |k_j|, so
// m_hat(row) = sqrt(|q_row|^2 * kmax2) >= every score -> exp2(s - m_hat)
// never overflows, and since num/denom scale identically the result is
// exact. m_hat is the same for all 4 scanning waves, so the cross-wave
// merge is a PLAIN SUM (no per-wave max rescale, no exps in merge).
// Hot loop per key j: 2 ds_read_b128 (k,v broadcast, amortized over 4 rows)
// + 40 VALU (per row: 4 FMA score chain initialized at -m_hat, exp2,
// l-add, 4 FMA PV).
constexpr int S  = 256;
constexpr int E  = 4;
constexpr int H1 = 8;
constexpr int H2 = 4;
constexpr int NW    = 4;       // waves per block
constexpr int CHUNK = S / NW;  // 64 keys per wave
constexpr int R     = 4;       // rows per lane (64 lanes * 4 = 256 rows)

__global__ __launch_bounds__(256, 4) void attn_mlp_kernel(
    const float* __restrict__ x,
    const float* __restrict__ Wq, const float* __restrict__ Wk, const float* __restrict__ Wv,
    const float* __restrict__ W1, const float* __restrict__ b1,
    const float* __restrict__ W2, const float* __restrict__ b2,
    const float* __restrict__ W3, const float* __restrict__ b3,
    float* __restrict__ out)
{
    const int b    = blockIdx.x;
    const int tid  = threadIdx.x;
    const int w    = tid >> 6;
    const int lane = tid & 63;

    __shared__ float4 q_lds[S];
    __shared__ float4 k_lds[S];
    __shared__ float4 v_lds[S];
    __shared__ float4 acc_lds[NW][S];
    __shared__ float  l_lds[NW][S];
    __shared__ float  kmax_lds[NW];

    // ---- Phase 1: q/k/v for row tid; block-wide max |k|^2 ----
    const float4 xr = *reinterpret_cast<const float4*>(x + ((size_t)b * S + tid) * E);
    const float xv[E] = {xr.x, xr.y, xr.z, xr.w};
    {
        float4 q, k, v;
        float* qp = &q.x; float* kp = &k.x; float* vp = &v.x;
        #pragma unroll
        for (int e = 0; e < E; ++e) {
            float aq = 0.f, ak = 0.f, av = 0.f;
            #pragma unroll
            for (int i = 0; i < E; ++i) {
                aq = fmaf(xv[i], Wq[i * E + e], aq);
                ak = fmaf(xv[i], Wk[i * E + e], ak);
                av = fmaf(xv[i], Wv[i * E + e], av);
            }
            qp[e] = aq * (0.5f * 1.44269504f);  // fold 1/sqrt(E) and log2(e)
            kp[e] = ak;
            vp[e] = av;
        }
        q_lds[tid] = q; k_lds[tid] = k; v_lds[tid] = v;

        // wave-reduce max of |k|^2
        float kk = fmaf(k.x, k.x, fmaf(k.y, k.y, fmaf(k.z, k.z, k.w * k.w)));
        #pragma unroll
        for (int off = 32; off > 0; off >>= 1)
            kk = fmaxf(kk, __shfl_xor(kk, off));
        if (lane == 0) kmax_lds[w] = kk;
    }
    __syncthreads();

    const float kmax2 = fmaxf(fmaxf(kmax_lds[0], kmax_lds[1]),
                              fmaxf(kmax_lds[2], kmax_lds[3]));

    // ---- rows handled by this lane: {lane + 64*rr}; per-row bound ----
    float4 qr[R];
    float  mh[R];
    #pragma unroll
    for (int rr = 0; rr < R; ++rr) {
        qr[rr] = q_lds[lane + 64 * rr];
        const float qq = fmaf(qr[rr].x, qr[rr].x,
                          fmaf(qr[rr].y, qr[rr].y,
                           fmaf(qr[rr].z, qr[rr].z, qr[rr].w * qr[rr].w)));
        mh[rr] = sqrtf(qq * kmax2);   // >= every scaled score for this row
    }

    // ---- Phase 2: one-pass scan of this wave's 64-key chunk ----
    const int j0 = w * CHUNK;
    float  l[R];
    float4 acc[R];
    #pragma unroll
    for (int rr = 0; rr < R; ++rr) {
        l[rr] = 0.f;
        acc[rr] = make_float4(0.f, 0.f, 0.f, 0.f);
    }

    #pragma unroll 4
    for (int j = 0; j < CHUNK; ++j) {
        const float4 k = k_lds[j0 + j];
        const float4 v = v_lds[j0 + j];
        #pragma unroll
        for (int rr = 0; rr < R; ++rr) {
            float s = fmaf(qr[rr].x, k.x,
                       fmaf(qr[rr].y, k.y,
                        fmaf(qr[rr].z, k.z,
                         fmaf(qr[rr].w, k.w, -mh[rr]))));
            const float p = __builtin_amdgcn_exp2f(s);  // s <= 0 always
            l[rr] += p;
            acc[rr].x = fmaf(p, v.x, acc[rr].x);
            acc[rr].y = fmaf(p, v.y, acc[rr].y);
            acc[rr].z = fmaf(p, v.z, acc[rr].z);
            acc[rr].w = fmaf(p, v.w, acc[rr].w);
        }
    }

    #pragma unroll
    for (int rr = 0; rr < R; ++rr) {
        const int row = lane + 64 * rr;
        acc_lds[w][row] = acc[rr];
        l_lds[w][row]   = l[rr];
    }
    __syncthreads();

    // ---- Phase 3: plain-sum merge for row tid, then MLP ----
    float lsum = 0.f;
    float ax = 0.f, ay = 0.f, az = 0.f, aw = 0.f;
    #pragma unroll
    for (int ww = 0; ww < NW; ++ww) {
        lsum += l_lds[ww][tid];
        const float4 a4 = acc_lds[ww][tid];
        ax += a4.x; ay += a4.y; az += a4.z; aw += a4.w;
    }
    const float inv = 1.0f / lsum;
    const float a[E] = {ax * inv, ay * inv, az * inv, aw * inv};

    float h1[H1];
    #pragma unroll
    for (int o = 0; o < H1; ++o) {
        float s = b1[o];
        #pragma unroll
        for (int i = 0; i < E; ++i) s = fmaf(a[i], W1[i * H1 + o], s);
        h1[o] = tanhf(s);
    }
    float h2[H2];
    #pragma unroll
    for (int o = 0; o < H2; ++o) {
        float s = b2[o];
        #pragma unroll
        for (int i = 0; i < H1; ++i) s = fmaf(h1[i], W2[i * H2 + o], s);
        h2[o] = tanhf(s);
    }
    float r = b3[0];
    #pragma unroll
    for (int i = 0; i < H2; ++i) r = fmaf(h2[i], W3[i], r);

    out[(size_t)b * S + tid] = r;
}

extern "C" void kernel_launch(void* const* d_in, const int* in_sizes, int n_in,
                              void* d_out, int out_size, void* d_ws, size_t ws_size,
                              hipStream_t stream) {
    const float* x  = (const float*)d_in[0];
    const float* Wq = (const float*)d_in[1];
    const float* Wk = (const float*)d_in[2];
    const float* Wv = (const float*)d_in[3];
    const float* W1 = (const float*)d_in[4];
    const float* b1 = (const float*)d_in[5];
    const float* W2 = (const float*)d_in[6];
    const float* b2 = (const float*)d_in[7];
    const float* W3 = (const float*)d_in[8];
    const float* b3 = (const float*)d_in[9];
    float* out = (float*)d_out;

    const int B = in_sizes[0] / (S * E);   // 1024
    attn_mlp_kernel<<<dim3(B), dim3(256), 0, stream>>>(
        x, Wq, Wk, Wv, W1, b1, W2, b2, W3, b3, out);
}